// Round 1
// 299.555 us; speedup vs baseline: 1.0092x; 1.0092x over previous
//
#include <hip/hip_runtime.h>

typedef _Float16 h16;
typedef __attribute__((ext_vector_type(4))) _Float16 half4v;
typedef __attribute__((ext_vector_type(8))) _Float16 half8v;
typedef __attribute__((ext_vector_type(4))) float f32x4;

static constexpr int Tn = 256;   // keys/values per head
static constexpr int Dn = 64;    // head dim
static constexpr int Sn = 128;   // query rows
static constexpr int KSTR = 72;  // halves; K tile [256][KSTR] (36864 B), reused as V^T chunks
static constexpr int PSTR = 40;  // halves; P chunk [32][PSTR], double-buffered per wave
static constexpr int VCH  = 64 * KSTR;  // 4608 halves: one V^T chunk [64 d][72 t] == 64 K rows

#define MFMA_F16 __builtin_amdgcn_mfma_f32_16x16x32_f16

// One block per (b,w) head. 4 waves; wave w owns S-strip [w*32, w*32+32).
// Pipelined V-over-QK^T: K rows [64c,64c+64) die after QK n-tiles 4c..4c+3, and V^T
// chunk c (chunk-major [c][64 d][72 t], 9216 B) occupies exactly those bytes. So:
//   issue V chunk-c loads (16 VGPRs) -> QK segment c overlaps the stream -> barrier
//   (its vmcnt drain waits exactly chunk c) -> scatter fp16 swizzled -> issue c+1.
// V streaming is thereby hidden under QK^T + softmax instead of serial-exposed.
__global__ __launch_bounds__(256, 2)
void attn_kernel(const float* __restrict__ Q, const float* __restrict__ K,
                 const float* __restrict__ V, float* __restrict__ O)
{
    __shared__ __align__(16) h16 KV[Tn * KSTR];          // 36864 B: K, progressively becomes V^T
    __shared__ __align__(16) h16 Pb[4 * 2 * 32 * PSTR];  // 20480 B: P chunks (dbuf x 4 waves)

    const int head = blockIdx.x;
    const int tid  = threadIdx.x;
    const int wave = tid >> 6;
    const int lane = tid & 63;
    const int quad = lane >> 4;
    const int l16  = lane & 15;

    const float* __restrict__ Kh = K + (size_t)head * (Tn * Dn);
    const float* __restrict__ Vh = V + (size_t)head * (Tn * Dn);
    float* __restrict__ Oh       = O + (size_t)head * (Sn * Dn);

    // ---- Q A-fragments (global fp32 -> fp16 regs). A[m=lane&15][k=quad*8+j].
    half8v qf[2][2];
#pragma unroll
    for (int m = 0; m < 2; ++m) {
        const float* qrow = Q + (wave * 32 + m * 16 + l16) * Dn;
#pragma unroll
        for (int kt = 0; kt < 2; ++kt) {
            float4 a = *reinterpret_cast<const float4*>(qrow + kt * 32 + quad * 8);
            float4 b = *reinterpret_cast<const float4*>(qrow + kt * 32 + quad * 8 + 4);
            half8v f;
            f[0] = (h16)a.x; f[1] = (h16)a.y; f[2] = (h16)a.z; f[3] = (h16)a.w;
            f[4] = (h16)b.x; f[5] = (h16)b.y; f[6] = (h16)b.z; f[7] = (h16)b.w;
            qf[m][kt] = f;
        }
    }

    // ---- stage K: coalesced float4 reads, b64 fp16 LDS writes, [t][d] stride KSTR
#pragma unroll
    for (int it = 0; it < 16; ++it) {
        int f   = it * 256 + tid;
        int row = f >> 4;          // t
        int c4  = (f & 15) << 2;   // d
        float4 kv = *reinterpret_cast<const float4*>(Kh + row * Dn + c4);
        half4v hv;
        hv[0] = (h16)kv.x; hv[1] = (h16)kv.y; hv[2] = (h16)kv.z; hv[3] = (h16)kv.w;
        *reinterpret_cast<half4v*>(&KV[row * KSTR + c4]) = hv;
    }
    __syncthreads();   // B1: K staged. (K loads can't sink below; V loads can't hoist above.)

    f32x4 acc[2][16] = {};
    float rinv[2][4];
    float4 vreg[4];    // in-flight V chunk: thread holds V[t = c*64 + wave*16 + l16][4 d-groups]

    // issue V chunk 0 loads — they stream while QK segment 0 computes
#pragma unroll
    for (int j = 0; j < 4; ++j) {
        int t     = 0 * 64 + wave * 16 + l16;
        int dbase = j * 16 + quad * 4;
        vreg[j] = *reinterpret_cast<const float4*>(Vh + t * Dn + dbase);
    }

#pragma unroll
    for (int c = 0; c < 4; ++c) {
        // ---- QK^T segment c: consumes K rows [64c, 64c+64); B[k=d][n=t] contiguous b128
#pragma unroll
        for (int nn = 0; nn < 4; ++nn) {
            int n = c * 4 + nn;
#pragma unroll
            for (int kt = 0; kt < 2; ++kt) {
                half8v bf = *reinterpret_cast<const half8v*>(
                    &KV[(n * 16 + l16) * KSTR + kt * 32 + quad * 8]);
                acc[0][n] = MFMA_F16(qf[0][kt], bf, acc[0][n], 0, 0, 0);
                acc[1][n] = MFMA_F16(qf[1][kt], bf, acc[1][n], 0, 0, 0);
            }
        }

        if (c == 3) {
            // ---- mask (p==0 -> -1e5) + softmax, fully in registers (covers chunk-3 stream)
#pragma unroll
            for (int m = 0; m < 2; ++m) {
#pragma unroll
                for (int r = 0; r < 4; ++r) {
                    float mx = -3.0e38f;
#pragma unroll
                    for (int n = 0; n < 16; ++n) {
                        float p = acc[m][n][r];
                        p = (p == 0.0f) ? -100000.0f : p;
                        acc[m][n][r] = p;
                        mx = fmaxf(mx, p);
                    }
                    mx = fmaxf(mx, __shfl_xor(mx, 1));
                    mx = fmaxf(mx, __shfl_xor(mx, 2));
                    mx = fmaxf(mx, __shfl_xor(mx, 4));
                    mx = fmaxf(mx, __shfl_xor(mx, 8));
                    float sm = 0.0f;
#pragma unroll
                    for (int n = 0; n < 16; ++n) {
                        float e = __expf(acc[m][n][r] - mx);
                        acc[m][n][r] = e;
                        sm += e;
                    }
                    sm += __shfl_xor(sm, 1);
                    sm += __shfl_xor(sm, 2);
                    sm += __shfl_xor(sm, 4);
                    sm += __shfl_xor(sm, 8);
                    rinv[m][r] = 1.0f / sm;
                }
            }
        }

        // All waves done reading K rows [64c,64c+64); implicit vmcnt drain = chunk c landed.
        __syncthreads();

        // ---- scatter V chunk c (fp16, XOR-swizzled) over the dead K rows.
        // Physical col: tc = trel ^ (quad<<3), quad == ((d>>2)&3) for all 4 written d
        // -> conflict-free b16 scatter writes, contiguous b128 reads in PV.
#pragma unroll
        for (int j = 0; j < 4; ++j) {
            int dbase = j * 16 + quad * 4;
            int trel  = wave * 16 + l16;
            int tc    = trel ^ (quad << 3);
            float4 vv = vreg[j];
            KV[c * VCH + (dbase + 0) * KSTR + tc] = (h16)vv.x;
            KV[c * VCH + (dbase + 1) * KSTR + tc] = (h16)vv.y;
            KV[c * VCH + (dbase + 2) * KSTR + tc] = (h16)vv.z;
            KV[c * VCH + (dbase + 3) * KSTR + tc] = (h16)vv.w;
        }

        // issue V chunk c+1 loads — stream overlaps QK segment c+1 (+ softmax for c=3)
        if (c < 3) {
#pragma unroll
            for (int j = 0; j < 4; ++j) {
                int t     = (c + 1) * 64 + wave * 16 + l16;
                int dbase = j * 16 + quad * 4;
                vreg[j] = *reinterpret_cast<const float4*>(Vh + t * Dn + dbase);
            }
        }
    }
    __syncthreads();   // V^T fully staged & visible to all waves

    // ---- O = P @ V over 8 chunks of 32 t. P: C-layout regs -> LDS (swizzled) -> A-frags.
    f32x4 oacc[2][4] = {};
    h16* Pw = &Pb[wave * 2 * 32 * PSTR];
#pragma unroll
    for (int c = 0; c < 8; ++c) {
        h16* buf = Pw + (c & 1) * 32 * PSTR;
#pragma unroll
        for (int m = 0; m < 2; ++m)
#pragma unroll
            for (int nn = 0; nn < 2; ++nn) {
                int n = 2 * c + nn;
#pragma unroll
                for (int r = 0; r < 4; ++r) {
                    int row = m * 16 + quad * 4 + r;
                    int col = (nn * 16 + l16) ^ (quad << 3);  // ((row>>2)&3)==quad
                    buf[row * PSTR + col] = (h16)acc[m][n][r];
                }
            }
        asm volatile("s_waitcnt lgkmcnt(0)" ::: "memory");  // LDS write->read hazard (wave-private)
        half8v pa[2];
#pragma unroll
        for (int m = 0; m < 2; ++m)
            pa[m] = *reinterpret_cast<const half8v*>(
                &buf[(m * 16 + l16) * PSTR + ((quad ^ (l16 >> 2)) << 3)]);
#pragma unroll
        for (int dt = 0; dt < 4; ++dt) {
            half8v vb = *reinterpret_cast<const half8v*>(
                &KV[(c >> 1) * VCH + (dt * 16 + l16) * KSTR + (c & 1) * 32 +
                    ((quad ^ (l16 >> 2)) << 3)]);
            oacc[0][dt] = MFMA_F16(pa[0], vb, oacc[0][dt], 0, 0, 0);
            oacc[1][dt] = MFMA_F16(pa[1], vb, oacc[1][dt], 0, 0, 0);
        }
    }

    // ---- epilogue: scale by 1/rowsum, coalesced-ish dword stores (16 lanes x 64B segments)
#pragma unroll
    for (int m = 0; m < 2; ++m)
#pragma unroll
        for (int dt = 0; dt < 4; ++dt)
#pragma unroll
            for (int r = 0; r < 4; ++r) {
                int s = wave * 32 + m * 16 + quad * 4 + r;
                Oh[s * Dn + dt * 16 + l16] = oacc[m][dt][r] * rinv[m][r];
            }
}

extern "C" void kernel_launch(void* const* d_in, const int* in_sizes, int n_in,
                              void* d_out, int out_size, void* d_ws, size_t ws_size,
                              hipStream_t stream) {
    (void)n_in; (void)out_size; (void)d_ws; (void)ws_size;
    const float* q = (const float*)d_in[0];
    const float* k = (const float*)d_in[1];
    const float* v = (const float*)d_in[2];
    float* o = (float*)d_out;
    const int heads = in_sizes[1] / (Tn * Dn);   // B*W = 2048
    attn_kernel<<<dim3(heads), dim3(256), 0, stream>>>(q, k, v, o);
}